// Round 5
// baseline (5159.122 us; speedup 1.0000x reference)
//
#include <hip/hip_runtime.h>

#define DD    512
#define SS    2048
#define NB    4
#define TOK   8192          // NB*SS
#define SEQM  4100
#define NACT  8
#define NBEAM 10
#define LNEPS 1e-5f
#define CH    2048          // tokens per chunk (chunk-outer beam pipeline)
#define NCHUNK (TOK / CH)
#define NLVL  7             // g-power levels 0..6
#define WJLD  (NLVL * DD)   // 3584, W1J row stride
#define SLOTS 6             // stored A levels 1..6
#define ATOK  (NBEAM * SLOTS * DD)   // 30720 floats per token in A ladder

// monotone mapping float -> uint (order-preserving for all finite floats)
__device__ __forceinline__ unsigned fmono(float f) {
  unsigned u = __float_as_uint(f);
  return (u & 0x80000000u) ? ~u : (u | 0x80000000u);
}

// ---------------------------------------------------------------------------
// G1: ct[b, s, d] = relu( sum_t x[b,d,t] * tril(weight0)[t,s] )
// ---------------------------------------------------------------------------
__global__ __launch_bounds__(256) void k_gemm_tril(
    const float* __restrict__ X, const float* __restrict__ W,
    float* __restrict__ Ct)
{
  __shared__ float As[16][132];
  __shared__ float Bs[16][132];
  const int tid = threadIdx.x;
  const int m0 = blockIdx.x * 128;
  const int n0 = blockIdx.y * 128;
  const int tm = tid >> 4, tn = tid & 15;
  float acc[8][8];
#pragma unroll
  for (int i = 0; i < 8; i++)
#pragma unroll
    for (int j = 0; j < 8; j++) acc[i][j] = 0.f;

  for (int k0 = n0; k0 < SS; k0 += 16) {
#pragma unroll
    for (int i = 0; i < 2; i++) {
      int id = tid + 256 * i;
      int r = id >> 2;
      int c4 = (id & 3) << 2;
      float4 av = *(const float4*)(X + (size_t)(m0 + r) * SS + k0 + c4);
      As[c4 + 0][r] = av.x; As[c4 + 1][r] = av.y;
      As[c4 + 2][r] = av.z; As[c4 + 3][r] = av.w;
    }
#pragma unroll
    for (int i = 0; i < 2; i++) {
      int id = tid + 256 * i;
      int r = id >> 5;
      int c = (id & 31) << 2;
      int kg = k0 + r;
      float4 bv = *(const float4*)(W + (size_t)kg * SEQM + n0 + c);
      int nc = n0 + c;
      bv.x = (kg >= nc + 0) ? bv.x : 0.f;
      bv.y = (kg >= nc + 1) ? bv.y : 0.f;
      bv.z = (kg >= nc + 2) ? bv.z : 0.f;
      bv.w = (kg >= nc + 3) ? bv.w : 0.f;
      *(float4*)&Bs[r][c] = bv;
    }
    __syncthreads();
#pragma unroll
    for (int kk = 0; kk < 16; kk++) {
      float4 a0 = *(const float4*)&As[kk][tm * 8];
      float4 a1 = *(const float4*)&As[kk][tm * 8 + 4];
      float4 b0 = *(const float4*)&Bs[kk][tn * 8];
      float4 b1 = *(const float4*)&Bs[kk][tn * 8 + 4];
      float a[8] = {a0.x, a0.y, a0.z, a0.w, a1.x, a1.y, a1.z, a1.w};
      float b[8] = {b0.x, b0.y, b0.z, b0.w, b1.x, b1.y, b1.z, b1.w};
#pragma unroll
      for (int i = 0; i < 8; i++)
#pragma unroll
        for (int j = 0; j < 8; j++) acc[i][j] = fmaf(a[i], b[j], acc[i][j]);
    }
    __syncthreads();
  }
  const int bI = m0 >> 9;
  const int d0 = (m0 & 511) + tm * 8;
#pragma unroll
  for (int j = 0; j < 8; j++) {
    int s = n0 + tn * 8 + j;
    float4 v0, v1;
    v0.x = fmaxf(acc[0][j], 0.f); v0.y = fmaxf(acc[1][j], 0.f);
    v0.z = fmaxf(acc[2][j], 0.f); v0.w = fmaxf(acc[3][j], 0.f);
    v1.x = fmaxf(acc[4][j], 0.f); v1.y = fmaxf(acc[5][j], 0.f);
    v1.z = fmaxf(acc[6][j], 0.f); v1.w = fmaxf(acc[7][j], 0.f);
    float* dst = Ct + ((size_t)bI * SS + s) * DD + d0;
    *(float4*)dst = v0;
    *(float4*)(dst + 4) = v1;
  }
}

// ---------------------------------------------------------------------------
// Generic [M,512] @ [512,512] GEMM (phase A + turn-0 logits GEMM).
// mode 0: +biasVec; mode 1: +biasVec, relu; mode 2: +gpre[m/rowsPerTok], relu.
// ---------------------------------------------------------------------------
__global__ __launch_bounds__(256) void k_gemm512(
    const float* __restrict__ A, const float* __restrict__ W,
    const float* __restrict__ biasVec, const float* __restrict__ gpre,
    int rowsPerTok, int strideTok, float* __restrict__ C, int mode)
{
  __shared__ float As[16][132];
  __shared__ float Bs[16][132];
  const int tid = threadIdx.x;
  const int m0 = blockIdx.x * 128;
  const int n0 = blockIdx.y * 128;
  const int tm = tid >> 4, tn = tid & 15;

  const int c4 = (tid & 3) << 2;
  const int r0 = tid >> 2;
  const int r1 = r0 + 64;
  const int gm0 = m0 + r0, gm1 = m0 + r1;
  const int t0i = gm0 / rowsPerTok, t1i = gm1 / rowsPerTok;
  const float* arow0 =
      A + ((size_t)t0i * strideTok + (gm0 - t0i * rowsPerTok)) * DD;
  const float* arow1 =
      A + ((size_t)t1i * strideTok + (gm1 - t1i * rowsPerTok)) * DD;

  float acc[8][8];
#pragma unroll
  for (int i = 0; i < 8; i++)
#pragma unroll
    for (int j = 0; j < 8; j++) acc[i][j] = 0.f;

  for (int k0 = 0; k0 < DD; k0 += 16) {
    {
      float4 av = *(const float4*)(arow0 + k0 + c4);
      As[c4 + 0][r0] = av.x; As[c4 + 1][r0] = av.y;
      As[c4 + 2][r0] = av.z; As[c4 + 3][r0] = av.w;
      float4 av1 = *(const float4*)(arow1 + k0 + c4);
      As[c4 + 0][r1] = av1.x; As[c4 + 1][r1] = av1.y;
      As[c4 + 2][r1] = av1.z; As[c4 + 3][r1] = av1.w;
    }
#pragma unroll
    for (int i = 0; i < 2; i++) {
      int id = tid + 256 * i;
      int r = id >> 5;
      int c = (id & 31) << 2;
      *(float4*)&Bs[r][c] =
          *(const float4*)(W + (size_t)(k0 + r) * DD + n0 + c);
    }
    __syncthreads();
#pragma unroll
    for (int kk = 0; kk < 16; kk++) {
      float4 a0 = *(const float4*)&As[kk][tm * 8];
      float4 a1 = *(const float4*)&As[kk][tm * 8 + 4];
      float4 b0 = *(const float4*)&Bs[kk][tn * 8];
      float4 b1 = *(const float4*)&Bs[kk][tn * 8 + 4];
      float a[8] = {a0.x, a0.y, a0.z, a0.w, a1.x, a1.y, a1.z, a1.w};
      float b[8] = {b0.x, b0.y, b0.z, b0.w, b1.x, b1.y, b1.z, b1.w};
#pragma unroll
      for (int i = 0; i < 8; i++)
#pragma unroll
        for (int j = 0; j < 8; j++) acc[i][j] = fmaf(a[i], b[j], acc[i][j]);
    }
    __syncthreads();
  }
#pragma unroll
  for (int i = 0; i < 8; i++) {
    int m = m0 + tm * 8 + i;
    const float* brow = (mode == 2) ? (gpre + (size_t)(m / rowsPerTok) * DD)
                                    : biasVec;
#pragma unroll
    for (int j = 0; j < 8; j++) {
      int n = n0 + tn * 8 + j;
      float v = acc[i][j] + brow[n];
      if (mode >= 1) v = fmaxf(v, 0.f);
      acc[i][j] = v;
    }
    float* dst = C + (size_t)m * DD + n0 + tn * 8;
    float4 w0v, w1v;
    w0v.x = acc[i][0]; w0v.y = acc[i][1]; w0v.z = acc[i][2]; w0v.w = acc[i][3];
    w1v.x = acc[i][4]; w1v.y = acc[i][5]; w1v.z = acc[i][6]; w1v.w = acc[i][7];
    *(float4*)dst = w0v;
    *(float4*)(dst + 4) = w1v;
  }
}

// ---------------------------------------------------------------------------
// Build W1J[d][L*512+n] = g[d]^L * W1[d][n], L=0..6 (W1 = gna_w1[:512,:]).
// ---------------------------------------------------------------------------
__global__ __launch_bounds__(256) void k_w1j(
    const float* __restrict__ W1, const float* __restrict__ g,
    float* __restrict__ W1J)
{
  const int d = blockIdx.x;
  const int tid = threadIdx.x;
  const float gd = g[d];
  const float w0 = W1[(size_t)d * DD + tid];
  const float w1 = W1[(size_t)d * DD + tid + 256];
  float p = 1.f;
  for (int L = 0; L < NLVL; L++) {
    W1J[(size_t)d * WJLD + L * DD + tid] = p * w0;
    W1J[(size_t)d * WJLD + L * DD + tid + 256] = p * w1;
    p *= gd;
  }
}

// ---------------------------------------------------------------------------
// Small[r][*] = srcrow_r @ W1J,  r<8: action[r], r=8: ones (-> q), r=9: ln_b (-> r).
// ---------------------------------------------------------------------------
__global__ __launch_bounds__(256) void k_small(
    const float* __restrict__ action, const float* __restrict__ lnb,
    const float* __restrict__ W1J, float* __restrict__ Small)
{
  const int r = blockIdx.x;
  const int n = blockIdx.y * 256 + threadIdx.x;
  float acc = 0.f;
  for (int d = 0; d < DD; d++) {
    float s = (r < 8) ? action[(size_t)r * DD + d] : ((r == 8) ? 1.f : lnb[d]);
    acc = fmaf(s, W1J[(size_t)d * WJLD + n], acc);
  }
  Small[(size_t)r * WJLD + n] = acc;
}

// ---------------------------------------------------------------------------
// A^(0) GEMM: [CH,512] @ W1J(levels 1..6) [512,3072] -> Abuf[tloc][beam0][slot][n]
// Wp passed pre-offset to level-1 block; row stride WJLD. C row stride ATOK.
// ---------------------------------------------------------------------------
__global__ __launch_bounds__(256) void k_gemmA(
    const float* __restrict__ A, const float* __restrict__ Wp,
    float* __restrict__ C)
{
  __shared__ float As[16][132];
  __shared__ float Bs[16][132];
  const int tid = threadIdx.x;
  const int m0 = blockIdx.x * 128;
  const int n0 = blockIdx.y * 128;
  const int tm = tid >> 4, tn = tid & 15;
  float acc[8][8];
#pragma unroll
  for (int i = 0; i < 8; i++)
#pragma unroll
    for (int j = 0; j < 8; j++) acc[i][j] = 0.f;

  for (int k0 = 0; k0 < DD; k0 += 16) {
#pragma unroll
    for (int i = 0; i < 2; i++) {
      int id = tid + 256 * i;
      int r = id >> 2;
      int c4 = (id & 3) << 2;
      float4 av = *(const float4*)(A + (size_t)(m0 + r) * DD + k0 + c4);
      As[c4 + 0][r] = av.x; As[c4 + 1][r] = av.y;
      As[c4 + 2][r] = av.z; As[c4 + 3][r] = av.w;
    }
#pragma unroll
    for (int i = 0; i < 2; i++) {
      int id = tid + 256 * i;
      int r = id >> 5;
      int c = (id & 31) << 2;
      *(float4*)&Bs[r][c] =
          *(const float4*)(Wp + (size_t)(k0 + r) * WJLD + n0 + c);
    }
    __syncthreads();
#pragma unroll
    for (int kk = 0; kk < 16; kk++) {
      float4 a0 = *(const float4*)&As[kk][tm * 8];
      float4 a1 = *(const float4*)&As[kk][tm * 8 + 4];
      float4 b0 = *(const float4*)&Bs[kk][tn * 8];
      float4 b1 = *(const float4*)&Bs[kk][tn * 8 + 4];
      float a[8] = {a0.x, a0.y, a0.z, a0.w, a1.x, a1.y, a1.z, a1.w};
      float b[8] = {b0.x, b0.y, b0.z, b0.w, b1.x, b1.y, b1.z, b1.w};
#pragma unroll
      for (int i = 0; i < 8; i++)
#pragma unroll
        for (int j = 0; j < 8; j++) acc[i][j] = fmaf(a[i], b[j], acc[i][j]);
    }
    __syncthreads();
  }
#pragma unroll
  for (int i = 0; i < 8; i++) {
    int m = m0 + tm * 8 + i;
    float* dst = C + (size_t)m * ATOK + n0 + tn * 8;
    float4 w0v, w1v;
    w0v.x = acc[i][0]; w0v.y = acc[i][1]; w0v.z = acc[i][2]; w0v.w = acc[i][3];
    w1v.x = acc[i][4]; w1v.y = acc[i][5]; w1v.z = acc[i][6]; w1v.w = acc[i][7];
    *(float4*)dst = w0v;
    *(float4*)(dst + 4) = w1v;
  }
}

// ---------------------------------------------------------------------------
// Turn-0 logits: logits[row][a] = sum_n h1[row][n]*W2[n][a] + b2[a].
// ---------------------------------------------------------------------------
__global__ __launch_bounds__(256) void k_logits(
    const float* __restrict__ H1, const float* __restrict__ W2,
    const float* __restrict__ b2, float* __restrict__ L)
{
  __shared__ float sW2[NACT][DD];
  const int tid = threadIdx.x;
  for (int idx = tid; idx < NACT * DD; idx += 256) {
    int n = idx & (DD - 1);
    int a = idx >> 9;
    sW2[a][n] = W2[(size_t)n * NACT + a];
  }
  __syncthreads();
  const int wv = tid >> 6, lane = tid & 63;
  const int rbase = blockIdx.x * 16 + wv * 4;
  for (int rr = 0; rr < 4; rr++) {
    const int row = rbase + rr;
    const float* hrow = H1 + (size_t)row * DD;
    float accv[NACT];
#pragma unroll
    for (int a = 0; a < NACT; a++) accv[a] = 0.f;
#pragma unroll
    for (int i = 0; i < 8; i++) {
      float h = hrow[lane + 64 * i];
#pragma unroll
      for (int a = 0; a < NACT; a++) accv[a] += h * sW2[a][lane + 64 * i];
    }
#pragma unroll
    for (int a = 0; a < NACT; a++)
#pragma unroll
      for (int off = 32; off; off >>= 1) accv[a] += __shfl_xor(accv[a], off, 64);
    float outv = accv[0];
#pragma unroll
    for (int a = 1; a < NACT; a++)
      if (lane == a) outv = accv[a];
    if (lane < NACT) L[(size_t)row * NACT + lane] = outv + b2[lane];
  }
}

// ---------------------------------------------------------------------------
// Per-token update: softmax -> combined -> stable top-k -> prob/act0 ->
// states (LN) + exports (parent, act, mu, inv) for the evolve kernel.
// ---------------------------------------------------------------------------
__global__ __launch_bounds__(256) void k_update2(
    const float* __restrict__ logits, int lgStride,
    const float* __restrict__ oldStates, int strideOld,
    float* __restrict__ statesC, float* __restrict__ prob,
    int* __restrict__ act0, int* __restrict__ parentC,
    int* __restrict__ actC, float* __restrict__ muC,
    float* __restrict__ invC, const float* __restrict__ action,
    const float* __restrict__ lng, const float* __restrict__ lnb,
    int turn, int beamNow, int beamNext, int writeStates, int chunkBase)
{
  __shared__ float sComb[NBEAM * NACT];
  __shared__ float sProbOld[NBEAM];
  __shared__ int   sAct0Old[NBEAM];
  __shared__ float sOld[NBEAM][DD];
  __shared__ int   sBeamIdx[NBEAM];
  __shared__ int   sActIdx[NBEAM];
  __shared__ int   sNewAct0[NBEAM];
  __shared__ float sNewProb[NBEAM];
  __shared__ float sRed[4];
  __shared__ float sMu, sInv;
  const int tid = threadIdx.x;
  const int tloc = blockIdx.x;
  const int tok = chunkBase + tloc;

  if (tid < beamNow) {
    sProbOld[tid] = (turn == 0) ? 1.0f : prob[tok * NBEAM + tid];
    sAct0Old[tid] = (turn == 0) ? 0 : act0[tok * NBEAM + tid];
  }
  __syncthreads();
  if (tid < beamNow) {
    const float* lg = logits + (size_t)tloc * lgStride + tid * NACT;
    float l[NACT];
    float mx = -1e30f;
#pragma unroll
    for (int a = 0; a < NACT; a++) { l[a] = lg[a]; mx = fmaxf(mx, l[a]); }
    float e[NACT];
    float sum = 0.f;
#pragma unroll
    for (int a = 0; a < NACT; a++) { e[a] = expf(l[a] - mx); sum += e[a]; }
    float p = sProbOld[tid];
#pragma unroll
    for (int a = 0; a < NACT; a++) sComb[tid * NACT + a] = p * (e[a] / sum);
  }
  __syncthreads();
  if (tid < 64) {
    const int n = beamNow * NACT;
    float v0 = (tid < n) ? sComb[tid] : -1.f;
    float v1 = (tid + 64 < n) ? sComb[tid + 64] : -1.f;
    for (int it = 0; it < beamNext; it++) {
      unsigned long long key0 =
          ((unsigned long long)fmono(v0) << 32) | (unsigned)(0xFFFFFFFFu - tid);
      unsigned long long key1 =
          ((unsigned long long)fmono(v1) << 32) |
          (unsigned)(0xFFFFFFFFu - (tid + 64));
      unsigned long long best = key0 > key1 ? key0 : key1;
#pragma unroll
      for (int off = 1; off < 64; off <<= 1) {
        unsigned long long o = __shfl_xor(best, off, 64);
        if (o > best) best = o;
      }
      int jw = (int)(0xFFFFFFFFu - (unsigned)(best & 0xFFFFFFFFu));
      if (tid == 0) {
        int bi = jw >> 3, ai = jw & 7;
        sBeamIdx[it] = bi;
        sActIdx[it] = ai;
        sNewProb[it] = sComb[jw];
        sNewAct0[it] = (turn == 0) ? ai : sAct0Old[bi];
      }
      if (jw == tid) v0 = -1.f;
      if (jw == tid + 64) v1 = -1.f;
    }
  }
  __syncthreads();
  if (tid < beamNext) {
    prob[tok * NBEAM + tid] = sNewProb[tid];
    act0[tok * NBEAM + tid] = sNewAct0[tid];
    if (writeStates) {
      parentC[tloc * NBEAM + tid] = sBeamIdx[tid];
      actC[tloc * NBEAM + tid] = sActIdx[tid];
    }
  }
  if (!writeStates) return;

  const float* oldBase = oldStates + (size_t)tloc * strideOld * DD;
  for (int idx = tid; idx < beamNow * DD; idx += 256)
    (&sOld[0][0])[idx] = oldBase[idx];
  __syncthreads();
  const int lane = tid & 63, wv = tid >> 6;
  for (int jb = 0; jb < beamNext; jb++) {
    int bi = sBeamIdx[jb], ai = sActIdx[jb];
    float v0 = sOld[bi][tid] + action[(size_t)ai * DD + tid];
    float v1 = sOld[bi][tid + 256] + action[(size_t)ai * DD + tid + 256];
    float s = v0 + v1;
#pragma unroll
    for (int off = 32; off; off >>= 1) s += __shfl_xor(s, off, 64);
    if (lane == 0) sRed[wv] = s;
    __syncthreads();
    if (tid == 0) sMu = (sRed[0] + sRed[1] + sRed[2] + sRed[3]) * (1.f / DD);
    __syncthreads();
    float mu = sMu;
    float h0 = v0 - mu, h1v = v1 - mu;
    float q = h0 * h0 + h1v * h1v;
#pragma unroll
    for (int off = 32; off; off >>= 1) q += __shfl_xor(q, off, 64);
    if (lane == 0) sRed[wv] = q;
    __syncthreads();
    if (tid == 0) {
      float inv_ =
          1.0f /
          sqrtf((sRed[0] + sRed[1] + sRed[2] + sRed[3]) * (1.f / DD) + LNEPS);
      sInv = inv_;
      muC[tloc * NBEAM + jb] = sMu;
      invC[tloc * NBEAM + jb] = inv_;
    }
    __syncthreads();
    float inv = sInv;
    float* dst = statesC + ((size_t)tloc * NBEAM + jb) * DD;
    dst[tid] = h0 * inv * lng[tid] + lnb[tid];
    dst[tid + 256] = h1v * inv * lng[tid + 256] + lnb[tid + 256];
    __syncthreads();
  }
}

// ---------------------------------------------------------------------------
// Evolve: A_L^{new}[jb] = inv*(A_{L+1}^{old}[p] + P_{L+1}[a]) - inv*mu*q_{L+1} + r_L
// (double internal arithmetic, fp32 storage). L=0 feeds inline logits:
// relu(A_0 + gpre) @ W2 + b2. Storage slot s holds level s+1.
// ---------------------------------------------------------------------------
__global__ __launch_bounds__(256) void k_evolve(
    const float* __restrict__ Aold, float* __restrict__ Anew,
    const float* __restrict__ Small, const float* __restrict__ gpre,
    const float* __restrict__ W2, const float* __restrict__ b2,
    float* __restrict__ logitsC, const int* __restrict__ parentC,
    const int* __restrict__ actC, const float* __restrict__ muC,
    const float* __restrict__ invC, int chunkBase, int turn, int beamNext)
{
  __shared__ float sW2[NACT][DD];
  __shared__ float sAcc[4][NACT];
  __shared__ int sPar[NBEAM];
  __shared__ int sAct[NBEAM];
  __shared__ float sMuA[NBEAM];
  __shared__ float sInvA[NBEAM];
  const int tid = threadIdx.x;
  const int tloc = blockIdx.x;
  const int tok = chunkBase + tloc;
  for (int idx = tid; idx < NACT * DD; idx += 256) {
    int n = idx & (DD - 1);
    int a = idx >> 9;
    sW2[a][n] = W2[(size_t)n * NACT + a];
  }
  if (tid < beamNext) {
    sPar[tid] = parentC[tloc * NBEAM + tid];
    sAct[tid] = actC[tloc * NBEAM + tid];
    sMuA[tid] = muC[tloc * NBEAM + tid];
    sInvA[tid] = invC[tloc * NBEAM + tid];
  }
  __syncthreads();
  const int n0 = tid, n1 = tid + 256;
  const float gp0 = gpre[(size_t)tok * DD + n0];
  const float gp1 = gpre[(size_t)tok * DD + n1];
  const int Jw = 5 - turn;   // new slots 0..Jw-1 written (levels 1..Jw)
  const float* qrow = Small + (size_t)8 * WJLD;
  const float* rrow = Small + (size_t)9 * WJLD;
  const int wv = tid >> 6, lane = tid & 63;

  for (int jb = 0; jb < beamNext; jb++) {
    const int p = sPar[jb], a = sAct[jb];
    const double inv = (double)sInvA[jb];
    const double invmu = inv * (double)sMuA[jb];
    const float* prow = Small + (size_t)a * WJLD;
    const float* abase = Aold + (size_t)tloc * ATOK + (size_t)p * (SLOTS * DD);
    // L = 0 -> inline logits
    {
      int cp0 = DD + n0, cp1 = DD + n1;          // level 1 columns of P/q
      double v0 = inv * ((double)abase[n0] + (double)prow[cp0]) -
                  invmu * (double)qrow[cp0] + (double)rrow[n0];
      double v1 = inv * ((double)abase[n1] + (double)prow[cp1]) -
                  invmu * (double)qrow[cp1] + (double)rrow[n1];
      float h0 = fmaxf((float)v0 + gp0, 0.f);
      float h1 = fmaxf((float)v1 + gp1, 0.f);
#pragma unroll
      for (int aa = 0; aa < NACT; aa++) {
        float pa = fmaf(h0, sW2[aa][n0], h1 * sW2[aa][n1]);
#pragma unroll
        for (int off = 32; off; off >>= 1) pa += __shfl_xor(pa, off, 64);
        if (lane == 0) sAcc[wv][aa] = pa;
      }
      __syncthreads();
      if (tid < NACT)
        logitsC[((size_t)tloc * NBEAM + jb) * NACT + tid] =
            sAcc[0][tid] + sAcc[1][tid] + sAcc[2][tid] + sAcc[3][tid] +
            b2[tid];
    }
    float* nbase = Anew + (size_t)tloc * ATOK + (size_t)jb * (SLOTS * DD);
    for (int L = 1; L <= Jw; L++) {
      int cl0 = L * DD + n0, cl1 = L * DD + n1;
      int cp0 = (L + 1) * DD + n0, cp1 = (L + 1) * DD + n1;
      double v0 = inv * ((double)abase[cl0] + (double)prow[cp0]) -
                  invmu * (double)qrow[cp0] + (double)rrow[cl0];
      double v1 = inv * ((double)abase[cl1] + (double)prow[cp1]) -
                  invmu * (double)qrow[cp1] + (double)rrow[cl1];
      nbase[(L - 1) * DD + n0] = (float)v0;
      nbase[(L - 1) * DD + n1] = (float)v1;
    }
    __syncthreads();   // guard sAcc reuse
  }
}

// ---------------------------------------------------------------------------
// Final: best beam -> first action -> LN stats of states0 + action[a].
// ---------------------------------------------------------------------------
__global__ __launch_bounds__(256) void k_final_prep(
    const float* __restrict__ prob, const int* __restrict__ act0,
    const float* __restrict__ states0, const float* __restrict__ action,
    int* __restrict__ abest, float* __restrict__ muA, float* __restrict__ invA)
{
  __shared__ int sA;
  __shared__ float sRed[4];
  __shared__ float sMu;
  const int tid = threadIdx.x;
  const int token = blockIdx.x;
  if (tid == 0) {
    float best = prob[token * NBEAM];
    int bi = 0;
    for (int j = 1; j < NBEAM; j++) {
      float v = prob[token * NBEAM + j];
      if (v > best) { best = v; bi = j; }
    }
    sA = act0[token * NBEAM + bi];
  }
  __syncthreads();
  const int a = sA;
  const int lane = tid & 63, wv = tid >> 6;
  float v0 = states0[(size_t)token * DD + tid] + action[(size_t)a * DD + tid];
  float v1 = states0[(size_t)token * DD + tid + 256] +
             action[(size_t)a * DD + tid + 256];
  float s = v0 + v1;
#pragma unroll
  for (int off = 32; off; off >>= 1) s += __shfl_xor(s, off, 64);
  if (lane == 0) sRed[wv] = s;
  __syncthreads();
  if (tid == 0) sMu = (sRed[0] + sRed[1] + sRed[2] + sRed[3]) * (1.f / DD);
  __syncthreads();
  float mu = sMu;
  float h0 = v0 - mu, h1v = v1 - mu;
  float q = h0 * h0 + h1v * h1v;
#pragma unroll
  for (int off = 32; off; off >>= 1) q += __shfl_xor(q, off, 64);
  if (lane == 0) sRed[wv] = q;
  __syncthreads();
  if (tid == 0) {
    float var = (sRed[0] + sRed[1] + sRed[2] + sRed[3]) * (1.f / DD);
    muA[token] = mu;
    invA[token] = 1.0f / sqrtf(var + LNEPS);
    abest[token] = a;
  }
}

// ---------------------------------------------------------------------------
// Final transposed write: out[b, d, s] via 32x64 LDS tile.
// ---------------------------------------------------------------------------
__global__ __launch_bounds__(256) void k_final_write(
    const float* __restrict__ states0, const float* __restrict__ action,
    const int* __restrict__ abest, const float* __restrict__ muA,
    const float* __restrict__ invA, const float* __restrict__ lng,
    const float* __restrict__ lnb, float* __restrict__ out)
{
  __shared__ float tile[32][65];
  const int t0 = blockIdx.x * 32;
  const int d0 = blockIdx.y * 64;
  const int tid = threadIdx.x;
  {
    int r = tid >> 3;
    int c = (tid & 7) * 8;
    int token = t0 + r;
    int a = abest[token];
    float mu = muA[token], inv = invA[token];
#pragma unroll
    for (int q = 0; q < 8; q++) {
      int d = d0 + c + q;
      float v = (states0[(size_t)token * DD + d] + action[(size_t)a * DD + d] -
                 mu) * inv * lng[d] + lnb[d];
      tile[r][c + q] = v;
    }
  }
  __syncthreads();
  {
    int dl = tid >> 2;
    int sc = (tid & 3) * 8;
    int b = t0 >> 11;
    int s0 = (t0 & 2047);
    float* dst = out + ((size_t)(b * DD + d0 + dl)) * SS + s0 + sc;
    float4 w0v, w1v;
    w0v.x = tile[sc + 0][dl]; w0v.y = tile[sc + 1][dl];
    w0v.z = tile[sc + 2][dl]; w0v.w = tile[sc + 3][dl];
    w1v.x = tile[sc + 4][dl]; w1v.y = tile[sc + 5][dl];
    w1v.z = tile[sc + 6][dl]; w1v.w = tile[sc + 7][dl];
    *(float4*)dst = w0v;
    *(float4*)(dst + 4) = w1v;
  }
}

// ---------------------------------------------------------------------------
extern "C" void kernel_launch(void* const* d_in, const int* in_sizes, int n_in,
                              void* d_out, int out_size, void* d_ws,
                              size_t ws_size, hipStream_t stream) {
  const float* x      = (const float*)d_in[0];
  const float* weight = (const float*)d_in[1];
  const float* c2s_w1 = (const float*)d_in[2];
  const float* c2s_b1 = (const float*)d_in[3];
  const float* c2s_w2 = (const float*)d_in[4];
  const float* c2s_b2 = (const float*)d_in[5];
  const float* eg_w1  = (const float*)d_in[6];
  const float* eg_b1  = (const float*)d_in[7];
  const float* eg_w2  = (const float*)d_in[8];
  const float* eg_b2  = (const float*)d_in[9];
  const float* gna_w1 = (const float*)d_in[10];
  const float* gna_b1 = (const float*)d_in[11];
  const float* gna_w2 = (const float*)d_in[12];
  const float* gna_b2 = (const float*)d_in[13];
  const float* action = (const float*)d_in[14];
  const float* ln_g   = (const float*)d_in[15];
  const float* ln_b   = (const float*)d_in[16];
  float* out = (float*)d_out;

  float* ws = (float*)d_ws;
  size_t o = 0;
  float* ct       = ws + o; o += (size_t)TOK * DD;
  float* htmp     = ws + o; o += (size_t)TOK * DD;
  float* states0  = ws + o; o += (size_t)TOK * DD;
  float* goal     = ws + o; o += (size_t)TOK * DD;
  float* gpre     = ws + o; o += (size_t)TOK * DD;
  float* W1J      = ws + o; o += (size_t)DD * WJLD;
  float* Small    = ws + o; o += (size_t)10 * WJLD;
  float* AbufA    = ws + o; o += (size_t)CH * ATOK;
  float* AbufB    = ws + o; o += (size_t)CH * ATOK;
  float* statesC  = ws + o; o += (size_t)CH * NBEAM * DD;
  float* h1c      = ws + o; o += (size_t)CH * DD;
  float* logits0c = ws + o; o += (size_t)CH * NACT;
  float* logitsC  = ws + o; o += (size_t)CH * NBEAM * NACT;
  float* probB    = ws + o; o += (size_t)TOK * NBEAM;
  int*   act0B    = (int*)(ws + o); o += (size_t)TOK * NBEAM;
  int*   parentC  = (int*)(ws + o); o += (size_t)CH * NBEAM;
  int*   actC     = (int*)(ws + o); o += (size_t)CH * NBEAM;
  float* muC      = ws + o; o += (size_t)CH * NBEAM;
  float* invC     = ws + o; o += (size_t)CH * NBEAM;
  int*   abest    = (int*)(ws + o); o += TOK;
  float* muA      = ws + o; o += TOK;
  float* invA     = ws + o; o += TOK;

  dim3 blk(256);
  // Phase A: causal mix + c2s/eg MLPs + goal's gna contribution (once).
  k_gemm_tril<<<dim3(16, 16), blk, 0, stream>>>(x, weight, ct);
  k_gemm512<<<dim3(TOK / 128, 4), blk, 0, stream>>>(ct, c2s_w1, c2s_b1, gpre, 1, 1, htmp, 1);
  k_gemm512<<<dim3(TOK / 128, 4), blk, 0, stream>>>(htmp, c2s_w2, c2s_b2, gpre, 1, 1, states0, 0);
  k_gemm512<<<dim3(TOK / 128, 4), blk, 0, stream>>>(ct, eg_w1, eg_b1, gpre, 1, 1, htmp, 1);
  k_gemm512<<<dim3(TOK / 128, 4), blk, 0, stream>>>(htmp, eg_w2, eg_b2, gpre, 1, 1, goal, 0);
  k_gemm512<<<dim3(TOK / 128, 4), blk, 0, stream>>>(goal, gna_w1 + (size_t)DD * DD, gna_b1, gpre, 1, 1, gpre, 0);

  // Prep: W1J ladder + small vectors (P, q, r).
  k_w1j<<<dim3(DD), blk, 0, stream>>>(gna_w1, ln_g, W1J);
  k_small<<<dim3(10, WJLD / 256), blk, 0, stream>>>(action, ln_b, W1J, Small);

  // Beam search, chunk-outer.
  for (int c = 0; c < NCHUNK; c++) {
    const int base = c * CH;
    k_gemmA<<<dim3(CH / 128, (SLOTS * DD) / 128), blk, 0, stream>>>(
        states0 + (size_t)base * DD, W1J + DD, AbufA);
    k_gemm512<<<dim3(CH / 128, 4), blk, 0, stream>>>(
        states0 + (size_t)base * DD, gna_w1, gna_b1,
        gpre + (size_t)base * DD, 1, 1, h1c, 2);
    k_logits<<<dim3(CH / 16), blk, 0, stream>>>(h1c, gna_w2, gna_b2, logits0c);

    float* Aold = AbufA;
    float* Anew = AbufB;
    for (int turn = 0; turn < 7; turn++) {
      int beamNow  = (turn == 0) ? 1 : ((turn == 1) ? 8 : 10);
      int beamNext = (turn == 0) ? 8 : 10;
      const float* lgp = (turn == 0) ? logits0c : logitsC;
      int lgs          = (turn == 0) ? NACT : (NBEAM * NACT);
      const float* oldS = (turn == 0) ? (states0 + (size_t)base * DD) : statesC;
      int strideOld     = (turn == 0) ? 1 : NBEAM;
      k_update2<<<dim3(CH), blk, 0, stream>>>(
          lgp, lgs, oldS, strideOld, statesC, probB, act0B, parentC, actC,
          muC, invC, action, ln_g, ln_b, turn, beamNow, beamNext,
          (turn < 6) ? 1 : 0, base);
      if (turn < 6) {
        k_evolve<<<dim3(CH), blk, 0, stream>>>(
            Aold, Anew, Small, gpre, gna_w2, gna_b2, logitsC, parentC, actC,
            muC, invC, base, turn, beamNext);
        float* t = Aold; Aold = Anew; Anew = t;
      }
    }
  }

  // Phase C: final selection + layernorm + transposed write.
  k_final_prep<<<dim3(TOK), blk, 0, stream>>>(probB, act0B, states0, action, abest, muA, invA);
  k_final_write<<<dim3(TOK / 32, DD / 64), blk, 0, stream>>>(states0, action, abest, muA, invA, ln_g, ln_b, out);

  (void)in_sizes; (void)n_in; (void)out_size; (void)ws_size;
}

// Round 6
// 3223.504 us; speedup vs baseline: 1.6005x; 1.6005x over previous
//
#include <hip/hip_runtime.h>

#define DD    512
#define SS    2048
#define NB    4
#define TOK   8192          // NB*SS
#define SEQM  4100
#define NACT  8
#define NBEAM 10
#define LNEPS 1e-5f

typedef unsigned short u16;
typedef short short8_t __attribute__((ext_vector_type(8)));
typedef float f32x4 __attribute__((ext_vector_type(4)));

// monotone mapping float -> uint (order-preserving for all finite floats)
__device__ __forceinline__ unsigned fmono(float f) {
  unsigned u = __float_as_uint(f);
  return (u & 0x80000000u) ? ~u : (u | 0x80000000u);
}

// float -> bf16 (RNE)
__device__ __forceinline__ u16 f2bf(float f) {
  unsigned u = __float_as_uint(f);
  unsigned r = u + 0x7FFFu + ((u >> 16) & 1u);
  return (u16)(r >> 16);
}

// ---------------------------------------------------------------------------
// G1: ct[b, s, d] = relu( sum_t x[b,d,t] * tril(weight0)[t,s] )
// ---------------------------------------------------------------------------
__global__ __launch_bounds__(256) void k_gemm_tril(
    const float* __restrict__ X, const float* __restrict__ W,
    float* __restrict__ Ct)
{
  __shared__ float As[16][132];
  __shared__ float Bs[16][132];
  const int tid = threadIdx.x;
  const int m0 = blockIdx.x * 128;
  const int n0 = blockIdx.y * 128;
  const int tm = tid >> 4, tn = tid & 15;
  float acc[8][8];
#pragma unroll
  for (int i = 0; i < 8; i++)
#pragma unroll
    for (int j = 0; j < 8; j++) acc[i][j] = 0.f;

  for (int k0 = n0; k0 < SS; k0 += 16) {
#pragma unroll
    for (int i = 0; i < 2; i++) {
      int id = tid + 256 * i;
      int r = id >> 2;
      int c4 = (id & 3) << 2;
      float4 av = *(const float4*)(X + (size_t)(m0 + r) * SS + k0 + c4);
      As[c4 + 0][r] = av.x; As[c4 + 1][r] = av.y;
      As[c4 + 2][r] = av.z; As[c4 + 3][r] = av.w;
    }
#pragma unroll
    for (int i = 0; i < 2; i++) {
      int id = tid + 256 * i;
      int r = id >> 5;
      int c = (id & 31) << 2;
      int kg = k0 + r;
      float4 bv = *(const float4*)(W + (size_t)kg * SEQM + n0 + c);
      int nc = n0 + c;
      bv.x = (kg >= nc + 0) ? bv.x : 0.f;
      bv.y = (kg >= nc + 1) ? bv.y : 0.f;
      bv.z = (kg >= nc + 2) ? bv.z : 0.f;
      bv.w = (kg >= nc + 3) ? bv.w : 0.f;
      *(float4*)&Bs[r][c] = bv;
    }
    __syncthreads();
#pragma unroll
    for (int kk = 0; kk < 16; kk++) {
      float4 a0 = *(const float4*)&As[kk][tm * 8];
      float4 a1 = *(const float4*)&As[kk][tm * 8 + 4];
      float4 b0 = *(const float4*)&Bs[kk][tn * 8];
      float4 b1 = *(const float4*)&Bs[kk][tn * 8 + 4];
      float a[8] = {a0.x, a0.y, a0.z, a0.w, a1.x, a1.y, a1.z, a1.w};
      float b[8] = {b0.x, b0.y, b0.z, b0.w, b1.x, b1.y, b1.z, b1.w};
#pragma unroll
      for (int i = 0; i < 8; i++)
#pragma unroll
        for (int j = 0; j < 8; j++) acc[i][j] = fmaf(a[i], b[j], acc[i][j]);
    }
    __syncthreads();
  }
  const int bI = m0 >> 9;
  const int d0 = (m0 & 511) + tm * 8;
#pragma unroll
  for (int j = 0; j < 8; j++) {
    int s = n0 + tn * 8 + j;
    float4 v0, v1;
    v0.x = fmaxf(acc[0][j], 0.f); v0.y = fmaxf(acc[1][j], 0.f);
    v0.z = fmaxf(acc[2][j], 0.f); v0.w = fmaxf(acc[3][j], 0.f);
    v1.x = fmaxf(acc[4][j], 0.f); v1.y = fmaxf(acc[5][j], 0.f);
    v1.z = fmaxf(acc[6][j], 0.f); v1.w = fmaxf(acc[7][j], 0.f);
    float* dst = Ct + ((size_t)bI * SS + s) * DD + d0;
    *(float4*)dst = v0;
    *(float4*)(dst + 4) = v1;
  }
}

// ---------------------------------------------------------------------------
// Generic [M,512] @ [512,512] fp32 GEMM (phase A only now).
// mode 0: +biasVec; mode 1: +biasVec, relu; mode 2: +gpre, relu.
// ---------------------------------------------------------------------------
__global__ __launch_bounds__(256) void k_gemm512(
    const float* __restrict__ A, const float* __restrict__ W,
    const float* __restrict__ biasVec, const float* __restrict__ gpre,
    int rowsPerTok, int strideTok, float* __restrict__ C, int mode)
{
  __shared__ float As[16][132];
  __shared__ float Bs[16][132];
  const int tid = threadIdx.x;
  const int m0 = blockIdx.x * 128;
  const int n0 = blockIdx.y * 128;
  const int tm = tid >> 4, tn = tid & 15;

  const int c4 = (tid & 3) << 2;
  const int r0 = tid >> 2;
  const int r1 = r0 + 64;
  const int gm0 = m0 + r0, gm1 = m0 + r1;
  const int t0i = gm0 / rowsPerTok, t1i = gm1 / rowsPerTok;
  const float* arow0 =
      A + ((size_t)t0i * strideTok + (gm0 - t0i * rowsPerTok)) * DD;
  const float* arow1 =
      A + ((size_t)t1i * strideTok + (gm1 - t1i * rowsPerTok)) * DD;

  float acc[8][8];
#pragma unroll
  for (int i = 0; i < 8; i++)
#pragma unroll
    for (int j = 0; j < 8; j++) acc[i][j] = 0.f;

  for (int k0 = 0; k0 < DD; k0 += 16) {
    {
      float4 av = *(const float4*)(arow0 + k0 + c4);
      As[c4 + 0][r0] = av.x; As[c4 + 1][r0] = av.y;
      As[c4 + 2][r0] = av.z; As[c4 + 3][r0] = av.w;
      float4 av1 = *(const float4*)(arow1 + k0 + c4);
      As[c4 + 0][r1] = av1.x; As[c4 + 1][r1] = av1.y;
      As[c4 + 2][r1] = av1.z; As[c4 + 3][r1] = av1.w;
    }
#pragma unroll
    for (int i = 0; i < 2; i++) {
      int id = tid + 256 * i;
      int r = id >> 5;
      int c = (id & 31) << 2;
      *(float4*)&Bs[r][c] =
          *(const float4*)(W + (size_t)(k0 + r) * DD + n0 + c);
    }
    __syncthreads();
#pragma unroll
    for (int kk = 0; kk < 16; kk++) {
      float4 a0 = *(const float4*)&As[kk][tm * 8];
      float4 a1 = *(const float4*)&As[kk][tm * 8 + 4];
      float4 b0 = *(const float4*)&Bs[kk][tn * 8];
      float4 b1 = *(const float4*)&Bs[kk][tn * 8 + 4];
      float a[8] = {a0.x, a0.y, a0.z, a0.w, a1.x, a1.y, a1.z, a1.w};
      float b[8] = {b0.x, b0.y, b0.z, b0.w, b1.x, b1.y, b1.z, b1.w};
#pragma unroll
      for (int i = 0; i < 8; i++)
#pragma unroll
        for (int j = 0; j < 8; j++) acc[i][j] = fmaf(a[i], b[j], acc[i][j]);
    }
    __syncthreads();
  }
#pragma unroll
  for (int i = 0; i < 8; i++) {
    int m = m0 + tm * 8 + i;
    const float* brow = (mode == 2) ? (gpre + (size_t)(m / rowsPerTok) * DD)
                                    : biasVec;
#pragma unroll
    for (int j = 0; j < 8; j++) {
      int n = n0 + tn * 8 + j;
      float v = acc[i][j] + brow[n];
      if (mode >= 1) v = fmaxf(v, 0.f);
      acc[i][j] = v;
    }
    float* dst = C + (size_t)m * DD + n0 + tn * 8;
    float4 w0v, w1v;
    w0v.x = acc[i][0]; w0v.y = acc[i][1]; w0v.z = acc[i][2]; w0v.w = acc[i][3];
    w1v.x = acc[i][4]; w1v.y = acc[i][5]; w1v.z = acc[i][6]; w1v.w = acc[i][7];
    *(float4*)dst = w0v;
    *(float4*)(dst + 4) = w1v;
  }
}

// ---------------------------------------------------------------------------
// Pre-split W1 (gna_w1[:512][:512], row-major [k][n]) into transposed bf16
// hi/lo arrays WT[n][k]: hi = bf16(v), lo = bf16(v - hi). Run once.
// ---------------------------------------------------------------------------
__global__ __launch_bounds__(256) void k_wsplit(
    const float* __restrict__ W, u16* __restrict__ WTh, u16* __restrict__ WTl)
{
  const int n = blockIdx.x;
  const int k = blockIdx.y * 256 + threadIdx.x;
  float v = W[(size_t)k * DD + n];
  u16 h = f2bf(v);
  float hf = __uint_as_float((unsigned)h << 16);
  u16 l = f2bf(v - hf);
  WTh[(size_t)n * DD + k] = h;
  WTl[(size_t)n * DD + k] = l;
}

// ---------------------------------------------------------------------------
// Split-precision bf16 MFMA GEMM: C = relu(A @ W1 + gpre[token]), A fp32
// [rows,512] (strided token layout), W pre-split WT_hi/WT_lo [n][k].
// D += al*wh + ah*wl + ah*wh  (al*wl dropped, ~2e-6 rel).
// Tile 64(M) x 128(N), BK=32, 4 waves (2x2), wave = 32x64 (2x4 MFMA tiles).
// mfma_f32_16x16x32_bf16 layouts: A[m=lane&15][k=quad*8+j],
// B[n=lane&15][k=quad*8+j], D[n=lane&15][m=quad*4+reg]  (doc-verified).
// ---------------------------------------------------------------------------
__global__ __launch_bounds__(256) void k_gemm_mfma(
    const float* __restrict__ A, const u16* __restrict__ WTh,
    const u16* __restrict__ WTl, const float* __restrict__ gpre,
    int rowsPerTok, int strideTok, float* __restrict__ C)
{
  __shared__ __attribute__((aligned(16))) u16 AsH[64][56];
  __shared__ __attribute__((aligned(16))) u16 AsL[64][56];
  __shared__ __attribute__((aligned(16))) u16 BsH[128][56];
  __shared__ __attribute__((aligned(16))) u16 BsL[128][56];
  const int tid = threadIdx.x;
  const int m0 = blockIdx.x * 64;
  const int n0 = blockIdx.y * 128;

  // staging assignments
  const int sar = tid >> 2;                 // A row 0..63
  const int sak = (tid & 3) * 8;            // A k offset {0,8,16,24}
  const int gm = m0 + sar;
  const int stok = gm / rowsPerTok;
  const float* arow =
      A + ((size_t)stok * strideTok + (gm - stok * rowsPerTok)) * DD;
  const int sbr = tid >> 1;                 // B n-row 0..127
  const int sbk = (tid & 1) * 16;           // B k offset {0,16}
  const u16* wth = WTh + (size_t)(n0 + sbr) * DD + sbk;
  const u16* wtl = WTl + (size_t)(n0 + sbr) * DD + sbk;

  // compute assignments
  const int lane = tid & 63;
  const int w = tid >> 6;
  const int wm = (w >> 1) * 32;
  const int wn = (w & 1) * 64;
  const int lrow = lane & 15;
  const int quad = lane >> 4;
  const int q8 = quad * 8;

  f32x4 acc[2][4];
  const f32x4 zz = {0.f, 0.f, 0.f, 0.f};
#pragma unroll
  for (int mt = 0; mt < 2; mt++)
#pragma unroll
    for (int nt = 0; nt < 4; nt++) acc[mt][nt] = zz;

  for (int k0 = 0; k0 < DD; k0 += 32) {
    __syncthreads();
    // stage A (fp32 -> hi/lo bf16)
    {
      float4 v0 = *(const float4*)(arow + k0 + sak);
      float4 v1 = *(const float4*)(arow + k0 + sak + 4);
      float vv[8] = {v0.x, v0.y, v0.z, v0.w, v1.x, v1.y, v1.z, v1.w};
      short8_t ph, pl;
#pragma unroll
      for (int j = 0; j < 8; j++) {
        u16 h = f2bf(vv[j]);
        float hf = __uint_as_float((unsigned)h << 16);
        ph[j] = (short)h;
        pl[j] = (short)f2bf(vv[j] - hf);
      }
      *(short8_t*)&AsH[sar][sak] = ph;
      *(short8_t*)&AsL[sar][sak] = pl;
    }
    // stage B (pre-split, transposed: [n][k], k contiguous)
    {
      *(short8_t*)&BsH[sbr][sbk] = *(const short8_t*)(wth + k0);
      *(short8_t*)&BsH[sbr][sbk + 8] = *(const short8_t*)(wth + k0 + 8);
      *(short8_t*)&BsL[sbr][sbk] = *(const short8_t*)(wtl + k0);
      *(short8_t*)&BsL[sbr][sbk + 8] = *(const short8_t*)(wtl + k0 + 8);
    }
    __syncthreads();
    short8_t ah[2], al[2], bh[4], bl[4];
#pragma unroll
    for (int mt = 0; mt < 2; mt++) {
      ah[mt] = *(const short8_t*)&AsH[wm + mt * 16 + lrow][q8];
      al[mt] = *(const short8_t*)&AsL[wm + mt * 16 + lrow][q8];
    }
#pragma unroll
    for (int nt = 0; nt < 4; nt++) {
      bh[nt] = *(const short8_t*)&BsH[wn + nt * 16 + lrow][q8];
      bl[nt] = *(const short8_t*)&BsL[wn + nt * 16 + lrow][q8];
    }
#pragma unroll
    for (int mt = 0; mt < 2; mt++)
#pragma unroll
      for (int nt = 0; nt < 4; nt++) {
        acc[mt][nt] = __builtin_amdgcn_mfma_f32_16x16x32_bf16(
            al[mt], bh[nt], acc[mt][nt], 0, 0, 0);
        acc[mt][nt] = __builtin_amdgcn_mfma_f32_16x16x32_bf16(
            ah[mt], bl[nt], acc[mt][nt], 0, 0, 0);
        acc[mt][nt] = __builtin_amdgcn_mfma_f32_16x16x32_bf16(
            ah[mt], bh[nt], acc[mt][nt], 0, 0, 0);
      }
  }
  // epilogue: + gpre[token][n], relu, store compact
#pragma unroll
  for (int mt = 0; mt < 2; mt++)
#pragma unroll
    for (int nt = 0; nt < 4; nt++) {
      const int n = n0 + wn + nt * 16 + lrow;
#pragma unroll
      for (int r = 0; r < 4; r++) {
        const int mc = m0 + wm + mt * 16 + quad * 4 + r;
        const int tk = mc / rowsPerTok;
        float v = acc[mt][nt][r] + gpre[(size_t)tk * DD + n];
        C[(size_t)mc * DD + n] = fmaxf(v, 0.f);
      }
    }
}

// ---------------------------------------------------------------------------
// logits[row][a] = sum_n h1[row][n] * gna_w2[n][a] + b2[a]
// ---------------------------------------------------------------------------
__global__ __launch_bounds__(256) void k_logits(
    const float* __restrict__ H1, const float* __restrict__ W2,
    const float* __restrict__ b2, float* __restrict__ L)
{
  __shared__ float sW2[NACT][DD];
  const int tid = threadIdx.x;
  for (int idx = tid; idx < NACT * DD; idx += 256) {
    int n = idx & (DD - 1);
    int a = idx >> 9;
    sW2[a][n] = W2[(size_t)n * NACT + a];
  }
  __syncthreads();
  const int wv = tid >> 6, lane = tid & 63;
  const int rbase = blockIdx.x * 16 + wv * 4;
  for (int rr = 0; rr < 4; rr++) {
    const int row = rbase + rr;
    const float* hrow = H1 + (size_t)row * DD;
    float accv[NACT];
#pragma unroll
    for (int a = 0; a < NACT; a++) accv[a] = 0.f;
#pragma unroll
    for (int i = 0; i < 8; i++) {
      float h = hrow[lane + 64 * i];
#pragma unroll
      for (int a = 0; a < NACT; a++) accv[a] += h * sW2[a][lane + 64 * i];
    }
#pragma unroll
    for (int a = 0; a < NACT; a++)
#pragma unroll
      for (int off = 32; off; off >>= 1) accv[a] += __shfl_xor(accv[a], off, 64);
    float outv = accv[0];
#pragma unroll
    for (int a = 1; a < NACT; a++)
      if (lane == a) outv = accv[a];
    if (lane < NACT) L[(size_t)row * NACT + lane] = outv + b2[lane];
  }
}

// ---------------------------------------------------------------------------
// Per-token: softmax -> combined -> stable top-k -> prob/act0 update ->
// (unless last turn) gather base, add action, layernorm, write new states.
// states written at FIXED stride NBEAM*DD (race-free).
// ---------------------------------------------------------------------------
__global__ __launch_bounds__(256) void k_update(
    const float* __restrict__ logits, const float* __restrict__ oldStates,
    float* __restrict__ states, float* __restrict__ prob,
    int* __restrict__ act0, const float* __restrict__ action,
    const float* __restrict__ lng, const float* __restrict__ lnb,
    int turn, int beamNow, int beamNext, int strideOld, int writeStates)
{
  __shared__ float sComb[NBEAM * NACT];
  __shared__ float sProbOld[NBEAM];
  __shared__ int   sAct0Old[NBEAM];
  __shared__ float sOld[NBEAM][DD];
  __shared__ int   sBeamIdx[NBEAM];
  __shared__ int   sActIdx[NBEAM];
  __shared__ int   sNewAct0[NBEAM];
  __shared__ float sNewProb[NBEAM];
  __shared__ float sRed[4];
  __shared__ float sMu, sInv;
  const int tid = threadIdx.x;
  const int token = blockIdx.x;

  if (tid < beamNow) {
    sProbOld[tid] = (turn == 0) ? 1.0f : prob[token * NBEAM + tid];
    sAct0Old[tid] = (turn == 0) ? 0 : act0[token * NBEAM + tid];
  }
  __syncthreads();
  if (tid < beamNow) {
    const float* lg = logits + ((size_t)token * beamNow + tid) * NACT;
    float l[NACT];
    float mx = -1e30f;
#pragma unroll
    for (int a = 0; a < NACT; a++) { l[a] = lg[a]; mx = fmaxf(mx, l[a]); }
    float e[NACT];
    float sum = 0.f;
#pragma unroll
    for (int a = 0; a < NACT; a++) { e[a] = expf(l[a] - mx); sum += e[a]; }
    float p = sProbOld[tid];
#pragma unroll
    for (int a = 0; a < NACT; a++) sComb[tid * NACT + a] = p * (e[a] / sum);
  }
  __syncthreads();
  if (tid < 64) {
    const int n = beamNow * NACT;
    float v0 = (tid < n) ? sComb[tid] : -1.f;
    float v1 = (tid + 64 < n) ? sComb[tid + 64] : -1.f;
    for (int it = 0; it < beamNext; it++) {
      unsigned long long key0 =
          ((unsigned long long)fmono(v0) << 32) | (unsigned)(0xFFFFFFFFu - tid);
      unsigned long long key1 =
          ((unsigned long long)fmono(v1) << 32) |
          (unsigned)(0xFFFFFFFFu - (tid + 64));
      unsigned long long best = key0 > key1 ? key0 : key1;
#pragma unroll
      for (int off = 1; off < 64; off <<= 1) {
        unsigned long long o = __shfl_xor(best, off, 64);
        if (o > best) best = o;
      }
      int jw = (int)(0xFFFFFFFFu - (unsigned)(best & 0xFFFFFFFFu));
      if (tid == 0) {
        int bi = jw >> 3, ai = jw & 7;
        sBeamIdx[it] = bi;
        sActIdx[it] = ai;
        sNewProb[it] = sComb[jw];
        sNewAct0[it] = (turn == 0) ? ai : sAct0Old[bi];
      }
      if (jw == tid) v0 = -1.f;
      if (jw == tid + 64) v1 = -1.f;
    }
  }
  __syncthreads();
  if (tid < beamNext) {
    prob[token * NBEAM + tid] = sNewProb[tid];
    act0[token * NBEAM + tid] = sNewAct0[tid];
  }
  if (!writeStates) return;

  const float* oldBase = oldStates + (size_t)token * strideOld * DD;
  for (int idx = tid; idx < beamNow * DD; idx += 256)
    (&sOld[0][0])[idx] = oldBase[idx];
  __syncthreads();
  const int lane = tid & 63, wv = tid >> 6;
  for (int jb = 0; jb < beamNext; jb++) {
    int bi = sBeamIdx[jb], ai = sActIdx[jb];
    float v0 = sOld[bi][tid] + action[(size_t)ai * DD + tid];
    float v1 = sOld[bi][tid + 256] + action[(size_t)ai * DD + tid + 256];
    float s = v0 + v1;
#pragma unroll
    for (int off = 32; off; off >>= 1) s += __shfl_xor(s, off, 64);
    if (lane == 0) sRed[wv] = s;
    __syncthreads();
    if (tid == 0) sMu = (sRed[0] + sRed[1] + sRed[2] + sRed[3]) * (1.f / DD);
    __syncthreads();
    float mu = sMu;
    float h0 = v0 - mu, h1v = v1 - mu;
    float q = h0 * h0 + h1v * h1v;
#pragma unroll
    for (int off = 32; off; off >>= 1) q += __shfl_xor(q, off, 64);
    if (lane == 0) sRed[wv] = q;
    __syncthreads();
    if (tid == 0)
      sInv = 1.0f /
             sqrtf((sRed[0] + sRed[1] + sRed[2] + sRed[3]) * (1.f / DD) + LNEPS);
    __syncthreads();
    float inv = sInv;
    float* dst = states + ((size_t)token * NBEAM + jb) * DD;
    dst[tid] = h0 * inv * lng[tid] + lnb[tid];
    dst[tid + 256] = h1v * inv * lng[tid + 256] + lnb[tid + 256];
    __syncthreads();
  }
}

// ---------------------------------------------------------------------------
// Final: best beam (argmax, first max), its first action, LN stats.
// ---------------------------------------------------------------------------
__global__ __launch_bounds__(256) void k_final_prep(
    const float* __restrict__ prob, const int* __restrict__ act0,
    const float* __restrict__ states0, const float* __restrict__ action,
    int* __restrict__ abest, float* __restrict__ muA, float* __restrict__ invA)
{
  __shared__ int sA;
  __shared__ float sRed[4];
  __shared__ float sMu;
  const int tid = threadIdx.x;
  const int token = blockIdx.x;
  if (tid == 0) {
    float best = prob[token * NBEAM];
    int bi = 0;
    for (int j = 1; j < NBEAM; j++) {
      float v = prob[token * NBEAM + j];
      if (v > best) { best = v; bi = j; }
    }
    sA = act0[token * NBEAM + bi];
  }
  __syncthreads();
  const int a = sA;
  const int lane = tid & 63, wv = tid >> 6;
  float v0 = states0[(size_t)token * DD + tid] + action[(size_t)a * DD + tid];
  float v1 = states0[(size_t)token * DD + tid + 256] +
             action[(size_t)a * DD + tid + 256];
  float s = v0 + v1;
#pragma unroll
  for (int off = 32; off; off >>= 1) s += __shfl_xor(s, off, 64);
  if (lane == 0) sRed[wv] = s;
  __syncthreads();
  if (tid == 0) sMu = (sRed[0] + sRed[1] + sRed[2] + sRed[3]) * (1.f / DD);
  __syncthreads();
  float mu = sMu;
  float h0 = v0 - mu, h1v = v1 - mu;
  float q = h0 * h0 + h1v * h1v;
#pragma unroll
  for (int off = 32; off; off >>= 1) q += __shfl_xor(q, off, 64);
  if (lane == 0) sRed[wv] = q;
  __syncthreads();
  if (tid == 0) {
    float var = (sRed[0] + sRed[1] + sRed[2] + sRed[3]) * (1.f / DD);
    muA[token] = mu;
    invA[token] = 1.0f / sqrtf(var + LNEPS);
    abest[token] = a;
  }
}

// ---------------------------------------------------------------------------
// Final transposed write: out[b, d, s] via 32x64 LDS tile.
// ---------------------------------------------------------------------------
__global__ __launch_bounds__(256) void k_final_write(
    const float* __restrict__ states0, const float* __restrict__ action,
    const int* __restrict__ abest, const float* __restrict__ muA,
    const float* __restrict__ invA, const float* __restrict__ lng,
    const float* __restrict__ lnb, float* __restrict__ out)
{
  __shared__ float tile[32][65];
  const int t0 = blockIdx.x * 32;
  const int d0 = blockIdx.y * 64;
  const int tid = threadIdx.x;
  {
    int r = tid >> 3;
    int c = (tid & 7) * 8;
    int token = t0 + r;
    int a = abest[token];
    float mu = muA[token], inv = invA[token];
#pragma unroll
    for (int q = 0; q < 8; q++) {
      int d = d0 + c + q;
      float v = (states0[(size_t)token * DD + d] + action[(size_t)a * DD + d] -
                 mu) * inv * lng[d] + lnb[d];
      tile[r][c + q] = v;
    }
  }
  __syncthreads();
  {
    int dl = tid >> 2;
    int sc = (tid & 3) * 8;
    int b = t0 >> 11;
    int s0 = (t0 & 2047);
    float* dst = out + ((size_t)(b * DD + d0 + dl)) * SS + s0 + sc;
    float4 w0v, w1v;
    w0v.x = tile[sc + 0][dl]; w0v.y = tile[sc + 1][dl];
    w0v.z = tile[sc + 2][dl]; w0v.w = tile[sc + 3][dl];
    w1v.x = tile[sc + 4][dl]; w1v.y = tile[sc + 5][dl];
    w1v.z = tile[sc + 6][dl]; w1v.w = tile[sc + 7][dl];
    *(float4*)dst = w0v;
    *(float4*)(dst + 4) = w1v;
  }
}

// ---------------------------------------------------------------------------
extern "C" void kernel_launch(void* const* d_in, const int* in_sizes, int n_in,
                              void* d_out, int out_size, void* d_ws,
                              size_t ws_size, hipStream_t stream) {
  const float* x      = (const float*)d_in[0];
  const float* weight = (const float*)d_in[1];
  const float* c2s_w1 = (const float*)d_in[2];
  const float* c2s_b1 = (const float*)d_in[3];
  const float* c2s_w2 = (const float*)d_in[4];
  const float* c2s_b2 = (const float*)d_in[5];
  const float* eg_w1  = (const float*)d_in[6];
  const float* eg_b1  = (const float*)d_in[7];
  const float* eg_w2  = (const float*)d_in[8];
  const float* eg_b2  = (const float*)d_in[9];
  const float* gna_w1 = (const float*)d_in[10];
  const float* gna_b1 = (const float*)d_in[11];
  const float* gna_w2 = (const float*)d_in[12];
  const float* gna_b2 = (const float*)d_in[13];
  const float* action = (const float*)d_in[14];
  const float* ln_g   = (const float*)d_in[15];
  const float* ln_b   = (const float*)d_in[16];
  float* out = (float*)d_out;

  float* ws = (float*)d_ws;
  size_t o = 0;
  float* ct      = ws + o; o += (size_t)TOK * DD;
  float* htmp    = ws + o; o += (size_t)TOK * DD;
  float* states0 = ws + o; o += (size_t)TOK * DD;
  float* goal    = ws + o; o += (size_t)TOK * DD;
  float* gpre    = ws + o; o += (size_t)TOK * DD;
  float* states  = ws + o; o += (size_t)TOK * NBEAM * DD;   // [token][10][D]
  float* h1      = ws + o; o += (size_t)TOK * NBEAM * DD;
  float* logitsB = ws + o; o += (size_t)TOK * NBEAM * NACT;
  float* probB   = ws + o; o += (size_t)TOK * NBEAM;
  int*   act0B   = (int*)(ws + o); o += (size_t)TOK * NBEAM;
  int*   abest   = (int*)(ws + o); o += TOK;
  float* muA     = ws + o; o += TOK;
  float* invA    = ws + o; o += TOK;
  u16*   WTh     = (u16*)(ws + o); o += (size_t)DD * DD / 2;
  u16*   WTl     = (u16*)(ws + o); o += (size_t)DD * DD / 2;

  dim3 blk(256);
  // Phase A: causal mix + c2s/eg MLPs + goal's gna contribution (once).
  k_gemm_tril<<<dim3(16, 16), blk, 0, stream>>>(x, weight, ct);
  k_gemm512<<<dim3(TOK / 128, 4), blk, 0, stream>>>(ct, c2s_w1, c2s_b1, gpre, 1, 1, htmp, 1);
  k_gemm512<<<dim3(TOK / 128, 4), blk, 0, stream>>>(htmp, c2s_w2, c2s_b2, gpre, 1, 1, states0, 0);
  k_gemm512<<<dim3(TOK / 128, 4), blk, 0, stream>>>(ct, eg_w1, eg_b1, gpre, 1, 1, htmp, 1);
  k_gemm512<<<dim3(TOK / 128, 4), blk, 0, stream>>>(htmp, eg_w2, eg_b2, gpre, 1, 1, goal, 0);
  k_gemm512<<<dim3(TOK / 128, 4), blk, 0, stream>>>(goal, gna_w1 + (size_t)DD * DD, gna_b1, gpre, 1, 1, gpre, 0);

  // Pre-split W1 for the MFMA turn GEMMs.
  k_wsplit<<<dim3(DD, 2), blk, 0, stream>>>(gna_w1, WTh, WTl);

  // Phase B: 7 beam turns, MFMA split-precision GEMM.
  for (int turn = 0; turn < 7; turn++) {
    int beamNow  = (turn == 0) ? 1 : ((turn == 1) ? 8 : 10);
    int beamNext = (turn == 0) ? 8 : 10;
    int rows = TOK * beamNow;
    const float* cur = (turn == 0) ? states0 : states;
    int strideOld    = (turn == 0) ? 1 : NBEAM;
    k_gemm_mfma<<<dim3(rows / 64, 4), blk, 0, stream>>>(
        cur, WTh, WTl, gpre, beamNow, strideOld, h1);
    k_logits<<<dim3(rows / 16), blk, 0, stream>>>(h1, gna_w2, gna_b2, logitsB);
    k_update<<<dim3(TOK), blk, 0, stream>>>(logitsB, cur, states, probB, act0B,
                                            action, ln_g, ln_b, turn, beamNow,
                                            beamNext, strideOld,
                                            (turn < 6) ? 1 : 0);
  }

  // Phase C: final selection + layernorm + transposed write.
  k_final_prep<<<dim3(TOK), blk, 0, stream>>>(probB, act0B, states0, action, abest, muA, invA);
  k_final_write<<<dim3(TOK / 32, DD / 64), blk, 0, stream>>>(states0, action, abest, muA, invA, ln_g, ln_b, out);

  (void)in_sizes; (void)n_in; (void)out_size; (void)ws_size;
}

// Round 7
// 2730.364 us; speedup vs baseline: 1.8895x; 1.1806x over previous
//
#include <hip/hip_runtime.h>

#define DD    512
#define SS    2048
#define NB    4
#define TOK   8192          // NB*SS
#define SEQM  4100
#define NACT  8
#define NBEAM 10
#define LNEPS 1e-5f

typedef unsigned short u16;
typedef short short8_t __attribute__((ext_vector_type(8)));
typedef float f32x4 __attribute__((ext_vector_type(4)));

// monotone mapping float -> uint (order-preserving for all finite floats)
__device__ __forceinline__ unsigned fmono(float f) {
  unsigned u = __float_as_uint(f);
  return (u & 0x80000000u) ? ~u : (u | 0x80000000u);
}

// float -> bf16 (RNE)
__device__ __forceinline__ u16 f2bf(float f) {
  unsigned u = __float_as_uint(f);
  unsigned r = u + 0x7FFFu + ((u >> 16) & 1u);
  return (u16)(r >> 16);
}

// ---------------------------------------------------------------------------
// Tril GEMM via split-precision bf16 MFMA:
// ct[b,s,d] = relu( sum_t x[b,d,t] * tril(w0)[t,s] )
// M=(b,d) rows of x (contiguous k), N=s (B=w0 transposed+masked in staging),
// both operands split hi/lo; D += ah*bh + ah*bl + al*bh.
// Tile 64M x 128N, BK=32, 4 waves. Epilogue: relu + transposed float4 store.
// ---------------------------------------------------------------------------
__global__ __launch_bounds__(256) void k_tril_mfma(
    const float* __restrict__ X, const float* __restrict__ W,
    float* __restrict__ Ct)
{
  __shared__ __attribute__((aligned(16))) u16 AsH[64][56];
  __shared__ __attribute__((aligned(16))) u16 AsL[64][56];
  __shared__ __attribute__((aligned(16))) u16 BsH[128][56];
  __shared__ __attribute__((aligned(16))) u16 BsL[128][56];
  const int tid = threadIdx.x;
  const int m0 = blockIdx.x * 64;
  const int n0 = blockIdx.y * 128;

  const int sar = tid >> 2;           // A row 0..63
  const int sak = (tid & 3) * 8;      // A k offset
  const float* arow = X + (size_t)(m0 + sar) * SS;
  const int sbk = tid >> 3;           // B k row 0..31
  const int sbc = (tid & 7) * 16;     // B col base

  const int lane = tid & 63;
  const int w = tid >> 6;
  const int wm = (w >> 1) * 32;
  const int wn = (w & 1) * 64;
  const int lrow = lane & 15;
  const int quad = lane >> 4;
  const int q8 = quad * 8;

  f32x4 acc[2][4];
  const f32x4 zz = {0.f, 0.f, 0.f, 0.f};
#pragma unroll
  for (int mt = 0; mt < 2; mt++)
#pragma unroll
    for (int nt = 0; nt < 4; nt++) acc[mt][nt] = zz;

  for (int k0 = n0; k0 < SS; k0 += 32) {
    __syncthreads();
    {  // stage A (x rows, fp32 -> hi/lo)
      float4 v0 = *(const float4*)(arow + k0 + sak);
      float4 v1 = *(const float4*)(arow + k0 + sak + 4);
      float vv[8] = {v0.x, v0.y, v0.z, v0.w, v1.x, v1.y, v1.z, v1.w};
      short8_t ph, pl;
#pragma unroll
      for (int j = 0; j < 8; j++) {
        u16 h = f2bf(vv[j]);
        float hf = __uint_as_float((unsigned)h << 16);
        ph[j] = (short)h;
        pl[j] = (short)f2bf(vv[j] - hf);
      }
      *(short8_t*)&AsH[sar][sak] = ph;
      *(short8_t*)&AsL[sar][sak] = pl;
    }
    {  // stage B (w0, masked tril, transposed to [n][k], split hi/lo)
      int kg = k0 + sbk;
      const float* wr = W + (size_t)kg * SEQM + n0 + sbc;
#pragma unroll
      for (int j4 = 0; j4 < 4; j4++) {
        float4 v = *(const float4*)(wr + j4 * 4);
        float vv[4] = {v.x, v.y, v.z, v.w};
        int ncb = n0 + sbc + j4 * 4;
#pragma unroll
        for (int j = 0; j < 4; j++) {
          float f = (kg >= ncb + j) ? vv[j] : 0.f;
          u16 h = f2bf(f);
          float hf = __uint_as_float((unsigned)h << 16);
          BsH[sbc + j4 * 4 + j][sbk] = h;
          BsL[sbc + j4 * 4 + j][sbk] = f2bf(f - hf);
        }
      }
    }
    __syncthreads();
    short8_t ah[2], al[2], bh[4], bl[4];
#pragma unroll
    for (int mt = 0; mt < 2; mt++) {
      ah[mt] = *(const short8_t*)&AsH[wm + mt * 16 + lrow][q8];
      al[mt] = *(const short8_t*)&AsL[wm + mt * 16 + lrow][q8];
    }
#pragma unroll
    for (int nt = 0; nt < 4; nt++) {
      bh[nt] = *(const short8_t*)&BsH[wn + nt * 16 + lrow][q8];
      bl[nt] = *(const short8_t*)&BsL[wn + nt * 16 + lrow][q8];
    }
#pragma unroll
    for (int mt = 0; mt < 2; mt++)
#pragma unroll
      for (int nt = 0; nt < 4; nt++) {
        acc[mt][nt] = __builtin_amdgcn_mfma_f32_16x16x32_bf16(
            al[mt], bh[nt], acc[mt][nt], 0, 0, 0);
        acc[mt][nt] = __builtin_amdgcn_mfma_f32_16x16x32_bf16(
            ah[mt], bl[nt], acc[mt][nt], 0, 0, 0);
        acc[mt][nt] = __builtin_amdgcn_mfma_f32_16x16x32_bf16(
            ah[mt], bh[nt], acc[mt][nt], 0, 0, 0);
      }
  }
  // epilogue: relu + transposed store (d contiguous -> float4)
  const int bI = m0 >> 9;
#pragma unroll
  for (int mt = 0; mt < 2; mt++)
#pragma unroll
    for (int nt = 0; nt < 4; nt++) {
      int s = n0 + wn + nt * 16 + lrow;
      int d0 = (m0 & 511) + wm + mt * 16 + quad * 4;
      float4 v;
      v.x = fmaxf(acc[mt][nt][0], 0.f);
      v.y = fmaxf(acc[mt][nt][1], 0.f);
      v.z = fmaxf(acc[mt][nt][2], 0.f);
      v.w = fmaxf(acc[mt][nt][3], 0.f);
      *(float4*)(Ct + ((size_t)bI * SS + s) * DD + d0) = v;
    }
}

// ---------------------------------------------------------------------------
// Generic [M,512] @ [512,512] fp32 GEMM (phase A only).
// mode 0: +biasVec; mode 1: +biasVec, relu; mode 2: +gpre, relu.
// ---------------------------------------------------------------------------
__global__ __launch_bounds__(256) void k_gemm512(
    const float* __restrict__ A, const float* __restrict__ W,
    const float* __restrict__ biasVec, const float* __restrict__ gpre,
    int rowsPerTok, int strideTok, float* __restrict__ C, int mode)
{
  __shared__ float As[16][132];
  __shared__ float Bs[16][132];
  const int tid = threadIdx.x;
  const int m0 = blockIdx.x * 128;
  const int n0 = blockIdx.y * 128;
  const int tm = tid >> 4, tn = tid & 15;

  const int c4 = (tid & 3) << 2;
  const int r0 = tid >> 2;
  const int r1 = r0 + 64;
  const int gm0 = m0 + r0, gm1 = m0 + r1;
  const int t0i = gm0 / rowsPerTok, t1i = gm1 / rowsPerTok;
  const float* arow0 =
      A + ((size_t)t0i * strideTok + (gm0 - t0i * rowsPerTok)) * DD;
  const float* arow1 =
      A + ((size_t)t1i * strideTok + (gm1 - t1i * rowsPerTok)) * DD;

  float acc[8][8];
#pragma unroll
  for (int i = 0; i < 8; i++)
#pragma unroll
    for (int j = 0; j < 8; j++) acc[i][j] = 0.f;

  for (int k0 = 0; k0 < DD; k0 += 16) {
    {
      float4 av = *(const float4*)(arow0 + k0 + c4);
      As[c4 + 0][r0] = av.x; As[c4 + 1][r0] = av.y;
      As[c4 + 2][r0] = av.z; As[c4 + 3][r0] = av.w;
      float4 av1 = *(const float4*)(arow1 + k0 + c4);
      As[c4 + 0][r1] = av1.x; As[c4 + 1][r1] = av1.y;
      As[c4 + 2][r1] = av1.z; As[c4 + 3][r1] = av1.w;
    }
#pragma unroll
    for (int i = 0; i < 2; i++) {
      int id = tid + 256 * i;
      int r = id >> 5;
      int c = (id & 31) << 2;
      *(float4*)&Bs[r][c] =
          *(const float4*)(W + (size_t)(k0 + r) * DD + n0 + c);
    }
    __syncthreads();
#pragma unroll
    for (int kk = 0; kk < 16; kk++) {
      float4 a0 = *(const float4*)&As[kk][tm * 8];
      float4 a1 = *(const float4*)&As[kk][tm * 8 + 4];
      float4 b0 = *(const float4*)&Bs[kk][tn * 8];
      float4 b1 = *(const float4*)&Bs[kk][tn * 8 + 4];
      float a[8] = {a0.x, a0.y, a0.z, a0.w, a1.x, a1.y, a1.z, a1.w};
      float b[8] = {b0.x, b0.y, b0.z, b0.w, b1.x, b1.y, b1.z, b1.w};
#pragma unroll
      for (int i = 0; i < 8; i++)
#pragma unroll
        for (int j = 0; j < 8; j++) acc[i][j] = fmaf(a[i], b[j], acc[i][j]);
    }
    __syncthreads();
  }
#pragma unroll
  for (int i = 0; i < 8; i++) {
    int m = m0 + tm * 8 + i;
    const float* brow = (mode == 2) ? (gpre + (size_t)(m / rowsPerTok) * DD)
                                    : biasVec;
#pragma unroll
    for (int j = 0; j < 8; j++) {
      int n = n0 + tn * 8 + j;
      float v = acc[i][j] + brow[n];
      if (mode >= 1) v = fmaxf(v, 0.f);
      acc[i][j] = v;
    }
    float* dst = C + (size_t)m * DD + n0 + tn * 8;
    float4 w0v, w1v;
    w0v.x = acc[i][0]; w0v.y = acc[i][1]; w0v.z = acc[i][2]; w0v.w = acc[i][3];
    w1v.x = acc[i][4]; w1v.y = acc[i][5]; w1v.z = acc[i][6]; w1v.w = acc[i][7];
    *(float4*)dst = w0v;
    *(float4*)(dst + 4) = w1v;
  }
}

// ---------------------------------------------------------------------------
// Pre-split W1 into transposed bf16 hi/lo arrays WT[n][k]. Run once.
// ---------------------------------------------------------------------------
__global__ __launch_bounds__(256) void k_wsplit(
    const float* __restrict__ W, u16* __restrict__ WTh, u16* __restrict__ WTl)
{
  const int n = blockIdx.x;
  const int k = blockIdx.y * 256 + threadIdx.x;
  float v = W[(size_t)k * DD + n];
  u16 h = f2bf(v);
  float hf = __uint_as_float((unsigned)h << 16);
  u16 l = f2bf(v - hf);
  WTh[(size_t)n * DD + k] = h;
  WTl[(size_t)n * DD + k] = l;
}

// ---------------------------------------------------------------------------
// Split-precision bf16 MFMA GEMM with FUSED partial logits:
// h = relu(A @ W1 + gpre[token]) is kept in an LDS overlay (never hits HBM);
// this block's 128-col slice is dotted with W2 and written as partial logits
// logitsPart[row][4 slices][NACT]. k_update sums the 4 partials + b2.
// Tile 64(M) x 128(N), BK=32, 4 waves.
// ---------------------------------------------------------------------------
__global__ __launch_bounds__(256) void k_gemm_mfma(
    const float* __restrict__ A, const u16* __restrict__ WTh,
    const u16* __restrict__ WTl, const float* __restrict__ gpre,
    const float* __restrict__ W2, int rowsPerTok, int strideTok,
    float* __restrict__ logitsPart)
{
  // staging buffers overlaid (after K-loop) by hs[64][132] + sW2t[8][132]
  __shared__ __attribute__((aligned(16))) unsigned char smem[43008];
  u16 (*AsH)[56] = (u16 (*)[56])(smem);              //  7168 B
  u16 (*AsL)[56] = (u16 (*)[56])(smem + 7168);       //  7168 B
  u16 (*BsH)[56] = (u16 (*)[56])(smem + 14336);      // 14336 B
  u16 (*BsL)[56] = (u16 (*)[56])(smem + 28672);      // 14336 B
  float (*hs)[132]   = (float (*)[132])(smem);           // 33792 B
  float (*sW2t)[132] = (float (*)[132])(smem + 33792);   //  4224 B (<=43008)

  const int tid = threadIdx.x;
  const int m0 = blockIdx.x * 64;
  const int n0 = blockIdx.y * 128;

  const int sar = tid >> 2;
  const int sak = (tid & 3) * 8;
  const int gm = m0 + sar;
  const int stok = gm / rowsPerTok;
  const float* arow =
      A + ((size_t)stok * strideTok + (gm - stok * rowsPerTok)) * DD;
  const int sbr = tid >> 1;
  const int sbk = (tid & 1) * 16;
  const u16* wth = WTh + (size_t)(n0 + sbr) * DD + sbk;
  const u16* wtl = WTl + (size_t)(n0 + sbr) * DD + sbk;

  const int lane = tid & 63;
  const int w = tid >> 6;
  const int wm = (w >> 1) * 32;
  const int wn = (w & 1) * 64;
  const int lrow = lane & 15;
  const int quad = lane >> 4;
  const int q8 = quad * 8;

  f32x4 acc[2][4];
  const f32x4 zz = {0.f, 0.f, 0.f, 0.f};
#pragma unroll
  for (int mt = 0; mt < 2; mt++)
#pragma unroll
    for (int nt = 0; nt < 4; nt++) acc[mt][nt] = zz;

  for (int k0 = 0; k0 < DD; k0 += 32) {
    __syncthreads();
    {
      float4 v0 = *(const float4*)(arow + k0 + sak);
      float4 v1 = *(const float4*)(arow + k0 + sak + 4);
      float vv[8] = {v0.x, v0.y, v0.z, v0.w, v1.x, v1.y, v1.z, v1.w};
      short8_t ph, pl;
#pragma unroll
      for (int j = 0; j < 8; j++) {
        u16 h = f2bf(vv[j]);
        float hf = __uint_as_float((unsigned)h << 16);
        ph[j] = (short)h;
        pl[j] = (short)f2bf(vv[j] - hf);
      }
      *(short8_t*)&AsH[sar][sak] = ph;
      *(short8_t*)&AsL[sar][sak] = pl;
    }
    {
      *(short8_t*)&BsH[sbr][sbk] = *(const short8_t*)(wth + k0);
      *(short8_t*)&BsH[sbr][sbk + 8] = *(const short8_t*)(wth + k0 + 8);
      *(short8_t*)&BsL[sbr][sbk] = *(const short8_t*)(wtl + k0);
      *(short8_t*)&BsL[sbr][sbk + 8] = *(const short8_t*)(wtl + k0 + 8);
    }
    __syncthreads();
    short8_t ah[2], al[2], bh[4], bl[4];
#pragma unroll
    for (int mt = 0; mt < 2; mt++) {
      ah[mt] = *(const short8_t*)&AsH[wm + mt * 16 + lrow][q8];
      al[mt] = *(const short8_t*)&AsL[wm + mt * 16 + lrow][q8];
    }
#pragma unroll
    for (int nt = 0; nt < 4; nt++) {
      bh[nt] = *(const short8_t*)&BsH[wn + nt * 16 + lrow][q8];
      bl[nt] = *(const short8_t*)&BsL[wn + nt * 16 + lrow][q8];
    }
#pragma unroll
    for (int mt = 0; mt < 2; mt++)
#pragma unroll
      for (int nt = 0; nt < 4; nt++) {
        acc[mt][nt] = __builtin_amdgcn_mfma_f32_16x16x32_bf16(
            al[mt], bh[nt], acc[mt][nt], 0, 0, 0);
        acc[mt][nt] = __builtin_amdgcn_mfma_f32_16x16x32_bf16(
            ah[mt], bl[nt], acc[mt][nt], 0, 0, 0);
        acc[mt][nt] = __builtin_amdgcn_mfma_f32_16x16x32_bf16(
            ah[mt], bh[nt], acc[mt][nt], 0, 0, 0);
      }
  }
  // ---- fused epilogue: h -> LDS overlay, then partial logits ----
  __syncthreads();
#pragma unroll
  for (int mt = 0; mt < 2; mt++)
#pragma unroll
    for (int nt = 0; nt < 4; nt++) {
      const int nl = wn + nt * 16 + lrow;
#pragma unroll
      for (int r = 0; r < 4; r++) {
        const int ml = wm + mt * 16 + quad * 4 + r;
        const int tk = (m0 + ml) / rowsPerTok;
        float v = acc[mt][nt][r] + gpre[(size_t)tk * DD + n0 + nl];
        hs[ml][nl] = fmaxf(v, 0.f);
      }
    }
  for (int idx = tid; idx < 128 * NACT; idx += 256)
    sW2t[idx & 7][idx >> 3] = W2[(size_t)n0 * NACT + idx];
  __syncthreads();
  {
    const int rowl = w * 16 + (lane >> 2);
    const int cq = lane & 3;
    float part[NACT];
#pragma unroll
    for (int a = 0; a < NACT; a++) part[a] = 0.f;
    for (int i = 0; i < 32; i++) {
      int c = cq + 4 * i;
      float h = hs[rowl][c];
#pragma unroll
      for (int a = 0; a < NACT; a++) part[a] = fmaf(h, sW2t[a][c], part[a]);
    }
#pragma unroll
    for (int a = 0; a < NACT; a++) {
      part[a] += __shfl_xor(part[a], 1, 64);
      part[a] += __shfl_xor(part[a], 2, 64);
    }
    if (cq == 0) {
      float* dst = logitsPart + (size_t)(m0 + rowl) * 32 + blockIdx.y * 8;
      float4 p0, p1;
      p0.x = part[0]; p0.y = part[1]; p0.z = part[2]; p0.w = part[3];
      p1.x = part[4]; p1.y = part[5]; p1.z = part[6]; p1.w = part[7];
      *(float4*)dst = p0;
      *(float4*)(dst + 4) = p1;
    }
  }
}

// ---------------------------------------------------------------------------
// Per-token: sum logit partials + b2 -> softmax -> combined -> stable top-k
// -> prob/act0 update -> (unless last turn) gather, add action, LN, store.
// ---------------------------------------------------------------------------
__global__ __launch_bounds__(256) void k_update(
    const float* __restrict__ logitsPart, const float* __restrict__ b2,
    const float* __restrict__ oldStates, float* __restrict__ states,
    float* __restrict__ prob, int* __restrict__ act0,
    const float* __restrict__ action, const float* __restrict__ lng,
    const float* __restrict__ lnb, int turn, int beamNow, int beamNext,
    int strideOld, int writeStates)
{
  __shared__ float sComb[NBEAM * NACT];
  __shared__ float sProbOld[NBEAM];
  __shared__ int   sAct0Old[NBEAM];
  __shared__ float sOld[NBEAM][DD];
  __shared__ int   sBeamIdx[NBEAM];
  __shared__ int   sActIdx[NBEAM];
  __shared__ int   sNewAct0[NBEAM];
  __shared__ float sNewProb[NBEAM];
  __shared__ float sRed[4];
  __shared__ float sMu, sInv;
  const int tid = threadIdx.x;
  const int token = blockIdx.x;

  if (tid < beamNow) {
    sProbOld[tid] = (turn == 0) ? 1.0f : prob[token * NBEAM + tid];
    sAct0Old[tid] = (turn == 0) ? 0 : act0[token * NBEAM + tid];
  }
  __syncthreads();
  if (tid < beamNow) {
    const float* lp = logitsPart + (size_t)(token * beamNow + tid) * 32;
    float l[NACT];
    float mx = -1e30f;
#pragma unroll
    for (int a = 0; a < NACT; a++) {
      l[a] = lp[a] + lp[8 + a] + lp[16 + a] + lp[24 + a] + b2[a];
      mx = fmaxf(mx, l[a]);
    }
    float e[NACT];
    float sum = 0.f;
#pragma unroll
    for (int a = 0; a < NACT; a++) { e[a] = expf(l[a] - mx); sum += e[a]; }
    float p = sProbOld[tid];
#pragma unroll
    for (int a = 0; a < NACT; a++) sComb[tid * NACT + a] = p * (e[a] / sum);
  }
  __syncthreads();
  if (tid < 64) {
    const int n = beamNow * NACT;
    float v0 = (tid < n) ? sComb[tid] : -1.f;
    float v1 = (tid + 64 < n) ? sComb[tid + 64] : -1.f;
    for (int it = 0; it < beamNext; it++) {
      unsigned long long key0 =
          ((unsigned long long)fmono(v0) << 32) | (unsigned)(0xFFFFFFFFu - tid);
      unsigned long long key1 =
          ((unsigned long long)fmono(v1) << 32) |
          (unsigned)(0xFFFFFFFFu - (tid + 64));
      unsigned long long best = key0 > key1 ? key0 : key1;
#pragma unroll
      for (int off = 1; off < 64; off <<= 1) {
        unsigned long long o = __shfl_xor(best, off, 64);
        if (o > best) best = o;
      }
      int jw = (int)(0xFFFFFFFFu - (unsigned)(best & 0xFFFFFFFFu));
      if (tid == 0) {
        int bi = jw >> 3, ai = jw & 7;
        sBeamIdx[it] = bi;
        sActIdx[it] = ai;
        sNewProb[it] = sComb[jw];
        sNewAct0[it] = (turn == 0) ? ai : sAct0Old[bi];
      }
      if (jw == tid) v0 = -1.f;
      if (jw == tid + 64) v1 = -1.f;
    }
  }
  __syncthreads();
  if (tid < beamNext) {
    prob[token * NBEAM + tid] = sNewProb[tid];
    act0[token * NBEAM + tid] = sNewAct0[tid];
  }
  if (!writeStates) return;

  const float* oldBase = oldStates + (size_t)token * strideOld * DD;
  for (int idx = tid; idx < beamNow * DD; idx += 256)
    (&sOld[0][0])[idx] = oldBase[idx];
  __syncthreads();
  const int lane = tid & 63, wv = tid >> 6;
  for (int jb = 0; jb < beamNext; jb++) {
    int bi = sBeamIdx[jb], ai = sActIdx[jb];
    float v0 = sOld[bi][tid] + action[(size_t)ai * DD + tid];
    float v1 = sOld[bi][tid + 256] + action[(size_t)ai * DD + tid + 256];
    float s = v0 + v1;
#pragma unroll
    for (int off = 32; off; off >>= 1) s += __shfl_xor(s, off, 64);
    if (lane == 0) sRed[wv] = s;
    __syncthreads();
    if (tid == 0) sMu = (sRed[0] + sRed[1] + sRed[2] + sRed[3]) * (1.f / DD);
    __syncthreads();
    float mu = sMu;
    float h0 = v0 - mu, h1v = v1 - mu;
    float q = h0 * h0 + h1v * h1v;
#pragma unroll
    for (int off = 32; off; off >>= 1) q += __shfl_xor(q, off, 64);
    if (lane == 0) sRed[wv] = q;
    __syncthreads();
    if (tid == 0)
      sInv = 1.0f /
             sqrtf((sRed[0] + sRed[1] + sRed[2] + sRed[3]) * (1.f / DD) + LNEPS);
    __syncthreads();
    float inv = sInv;
    float* dst = states + ((size_t)token * NBEAM + jb) * DD;
    dst[tid] = h0 * inv * lng[tid] + lnb[tid];
    dst[tid + 256] = h1v * inv * lng[tid + 256] + lnb[tid + 256];
    __syncthreads();
  }
}

// ---------------------------------------------------------------------------
// Final: best beam (argmax, first max), its first action, LN stats.
// ---------------------------------------------------------------------------
__global__ __launch_bounds__(256) void k_final_prep(
    const float* __restrict__ prob, const int* __restrict__ act0,
    const float* __restrict__ states0, const float* __restrict__ action,
    int* __restrict__ abest, float* __restrict__ muA, float* __restrict__ invA)
{
  __shared__ int sA;
  __shared__ float sRed[4];
  __shared__ float sMu;
  const int tid = threadIdx.x;
  const int token = blockIdx.x;
  if (tid == 0) {
    float best = prob[token * NBEAM];
    int bi = 0;
    for (int j = 1; j < NBEAM; j++) {
      float v = prob[token * NBEAM + j];
      if (v > best) { best = v; bi = j; }
    }
    sA = act0[token * NBEAM + bi];
  }
  __syncthreads();
  const int a = sA;
  const int lane = tid & 63, wv = tid >> 6;
  float v0 = states0[(size_t)token * DD + tid] + action[(size_t)a * DD + tid];
  float v1 = states0[(size_t)token * DD + tid + 256] +
             action[(size_t)a * DD + tid + 256];
  float s = v0 + v1;
#pragma unroll
  for (int off = 32; off; off >>= 1) s += __shfl_xor(s, off, 64);
  if (lane == 0) sRed[wv] = s;
  __syncthreads();
  if (tid == 0) sMu = (sRed[0] + sRed[1] + sRed[2] + sRed[3]) * (1.f / DD);
  __syncthreads();
  float mu = sMu;
  float h0 = v0 - mu, h1v = v1 - mu;
  float q = h0 * h0 + h1v * h1v;
#pragma unroll
  for (int off = 32; off; off >>= 1) q += __shfl_xor(q, off, 64);
  if (lane == 0) sRed[wv] = q;
  __syncthreads();
  if (tid == 0) {
    float var = (sRed[0] + sRed[1] + sRed[2] + sRed[3]) * (1.f / DD);
    muA[token] = mu;
    invA[token] = 1.0f / sqrtf(var + LNEPS);
    abest[token] = a;
  }
}

// ---------------------------------------------------------------------------
// Final transposed write: out[b, d, s] via 32x64 LDS tile.
// ---------------------------------------------------------------------------
__global__ __launch_bounds__(256) void k_final_write(
    const float* __restrict__ states0, const float* __restrict__ action,
    const int* __restrict__ abest, const float* __restrict__ muA,
    const float* __restrict__ invA, const float* __restrict__ lng,
    const float* __restrict__ lnb, float* __restrict__ out)
{
  __shared__ float tile[32][65];
  const int t0 = blockIdx.x * 32;
  const int d0 = blockIdx.y * 64;
  const int tid = threadIdx.x;
  {
    int r = tid >> 3;
    int c = (tid & 7) * 8;
    int token = t0 + r;
    int a = abest[token];
    float mu = muA[token], inv = invA[token];
#pragma unroll
    for (int q = 0; q < 8; q++) {
      int d = d0 + c + q;
      float v = (states0[(size_t)token * DD + d] + action[(size_t)a * DD + d] -
                 mu) * inv * lng[d] + lnb[d];
      tile[r][c + q] = v;
    }
  }
  __syncthreads();
  {
    int dl = tid >> 2;
    int sc = (tid & 3) * 8;
    int b = t0 >> 11;
    int s0 = (t0 & 2047);
    float* dst = out + ((size_t)(b * DD + d0 + dl)) * SS + s0 + sc;
    float4 w0v, w1v;
    w0v.x = tile[sc + 0][dl]; w0v.y = tile[sc + 1][dl];
    w0v.z = tile[sc + 2][dl]; w0v.w = tile[sc + 3][dl];
    w1v.x = tile[sc + 4][dl]; w1v.y = tile[sc + 5][dl];
    w1v.z = tile[sc + 6][dl]; w1v.w = tile[sc + 7][dl];
    *(float4*)dst = w0v;
    *(float4*)(dst + 4) = w1v;
  }
}

// ---------------------------------------------------------------------------
extern "C" void kernel_launch(void* const* d_in, const int* in_sizes, int n_in,
                              void* d_out, int out_size, void* d_ws,
                              size_t ws_size, hipStream_t stream) {
  const float* x      = (const float*)d_in[0];
  const float* weight = (const float*)d_in[1];
  const float* c2s_w1 = (const float*)d_in[2];
  const float* c2s_b1 = (const float*)d_in[3];
  const float* c2s_w2 = (const float*)d_in[4];
  const float* c2s_b2 = (const float*)d_in[5];
  const float* eg_w1  = (const float*)d_in[6];
  const float* eg_b1  = (const float*)d_in[7];
  const float* eg_w2  = (const float*)d_in[8];
  const float* eg_b2  = (const float*)d_in[9];
  const float* gna_w1 = (const float*)d_in[10];
  const float* gna_b1 = (const float*)d_in[11];
  const float* gna_w2 = (const float*)d_in[12];
  const float* gna_b2 = (const float*)d_in[13];
  const float* action = (const float*)d_in[14];
  const float* ln_g   = (const float*)d_in[15];
  const float* ln_b   = (const float*)d_in[16];
  float* out = (float*)d_out;

  float* ws = (float*)d_ws;
  size_t o = 0;
  float* ct       = ws + o; o += (size_t)TOK * DD;
  float* htmp     = ws + o; o += (size_t)TOK * DD;
  float* states0  = ws + o; o += (size_t)TOK * DD;
  float* goal     = ws + o; o += (size_t)TOK * DD;
  float* gpre     = ws + o; o += (size_t)TOK * DD;
  float* states   = ws + o; o += (size_t)TOK * NBEAM * DD;  // [token][10][D]
  float* logitsP  = ws + o; o += (size_t)TOK * NBEAM * 32;  // partial logits
  float* probB    = ws + o; o += (size_t)TOK * NBEAM;
  int*   act0B    = (int*)(ws + o); o += (size_t)TOK * NBEAM;
  int*   abest    = (int*)(ws + o); o += TOK;
  float* muA      = ws + o; o += TOK;
  float* invA     = ws + o; o += TOK;
  u16*   WTh      = (u16*)(ws + o); o += (size_t)DD * DD / 2;
  u16*   WTl      = (u16*)(ws + o); o += (size_t)DD * DD / 2;

  dim3 blk(256);
  // Phase A: causal mix (MFMA) + c2s/eg MLPs + goal's gna contribution.
  k_tril_mfma<<<dim3(2048 / 64, SS / 128), blk, 0, stream>>>(x, weight, ct);
  k_gemm512<<<dim3(TOK / 128, 4), blk, 0, stream>>>(ct, c2s_w1, c2s_b1, gpre, 1, 1, htmp, 1);
  k_gemm512<<<dim3(TOK / 128, 4), blk, 0, stream>>>(htmp, c2s_w2, c2s_b2, gpre, 1, 1, states0, 0);
  k_gemm512<<<dim3(TOK / 128, 4), blk, 0, stream>>>(ct, eg_w1, eg_b1, gpre, 1, 1, htmp, 1);
  k_gemm512<<<dim3(TOK / 128, 4), blk, 0, stream>>>(htmp, eg_w2, eg_b2, gpre, 1, 1, goal, 0);
  k_gemm512<<<dim3(TOK / 128, 4), blk, 0, stream>>>(goal, gna_w1 + (size_t)DD * DD, gna_b1, gpre, 1, 1, gpre, 0);

  // Pre-split W1 for the MFMA turn GEMMs.
  k_wsplit<<<dim3(DD, 2), blk, 0, stream>>>(gna_w1, WTh, WTl);

  // Phase B: 7 beam turns. GEMM + fused logits, then update.
  for (int turn = 0; turn < 7; turn++) {
    int beamNow  = (turn == 0) ? 1 : ((turn == 1) ? 8 : 10);
    int beamNext = (turn == 0) ? 8 : 10;
    int rows = TOK * beamNow;
    const float* cur = (turn == 0) ? states0 : states;
    int strideOld    = (turn == 0) ? 1 : NBEAM;
    k_gemm_mfma<<<dim3(rows / 64, 4), blk, 0, stream>>>(
        cur, WTh, WTl, gpre, gna_w2, beamNow, strideOld, logitsP);
    k_update<<<dim3(TOK), blk, 0, stream>>>(
        logitsP, gna_b2, cur, states, probB, act0B, action, ln_g, ln_b,
        turn, beamNow, beamNext, strideOld, (turn < 6) ? 1 : 0);
  }

  // Phase C: final selection + layernorm + transposed write.
  k_final_prep<<<dim3(TOK), blk, 0, stream>>>(probB, act0B, states0, action, abest, muA, invA);
  k_final_write<<<dim3(TOK / 32, DD / 64), blk, 0, stream>>>(states0, action, abest, muA, invA, ln_g, ln_b, out);

  (void)in_sizes; (void)n_in; (void)out_size; (void)ws_size;
}